// Round 1
// baseline (7215.164 us; speedup 1.0000x reference)
//
#include <hip/hip_runtime.h>
#include <math.h>

#define SUB 20      // sub_no
#define NC 19       // sub_no - 1
#define TSYN 200
#define THIST 50
#define BNUM 3

// ---------------------------------------------------------------------------
// k_prep: assignment indices from one-hot C_syn, plus the three alpha-basis
// kernels (syn with delta shift, hist, prop). All tiny, one launch.
// ---------------------------------------------------------------------------
__global__ void k_prep(const float* __restrict__ C_syn_e, const float* __restrict__ C_syn_i,
                       const float* __restrict__ W_ns_syn, const float* __restrict__ Delta_ns_syn,
                       const float* __restrict__ W_ns_hist, const float* __restrict__ W_ns_prop,
                       int* __restrict__ ae, int* __restrict__ ai,
                       float* __restrict__ ke, float* __restrict__ ki,
                       float* __restrict__ histk, float* __restrict__ propk,
                       int E, int I)
{
    int idx = blockIdx.x * blockDim.x + threadIdx.x;
    if (idx < E) {
        int a = 0;
        for (int s = 0; s < SUB; ++s) if (C_syn_e[(size_t)s * E + idx] != 0.f) a = s;
        ae[idx] = a;
        return;
    }
    idx -= E;
    if (idx < I) {
        int a = 0;
        for (int s = 0; s < SUB; ++s) if (C_syn_i[(size_t)s * I + idx] != 0.f) a = s;
        ai[idx] = a;
        return;
    }
    idx -= I;
    if (idx < SUB * 2 * TSYN) {
        int j   = idx % TSYN;
        int rem = idx / TSYN;
        int c2  = rem & 1;
        int s   = rem >> 1;
        float delta = expf(Delta_ns_syn[s * 2 + c2]);
        float ts = fmaxf((float)j - delta, 0.f);
        float acc = 0.f;
        for (int b = 0; b < BNUM; ++b) {
            float tau = expf((float)b);
            float tt = ts / tau;
            acc += W_ns_syn[s * 6 + b * 2 + c2] * tt * expf(-tt);
        }
        if (c2 == 0) ke[s * TSYN + j] = acc; else ki[s * TSYN + j] = acc;
        return;
    }
    idx -= SUB * 2 * TSYN;
    if (idx < NC * THIST) {
        int j = idx % THIST, c = idx / THIST;
        float acc = 0.f;
        for (int b = 0; b < BNUM; ++b) {
            float tau = expf((float)b);
            float tt = (float)j / tau;
            acc += W_ns_hist[c * 3 + b] * tt * expf(-tt);
        }
        histk[c * THIST + j] = acc;
        return;
    }
    idx -= NC * THIST;
    if (idx < SUB * THIST) {
        int j = idx % THIST, s = idx / THIST;
        float acc = 0.f;
        for (int b = 0; b < BNUM; ++b) {
            float tau = expf((float)b);
            float tt = (float)j / tau;
            acc += W_ns_prop[s * 3 + b] * tt * expf(-tt);
        }
        propk[s * THIST + j] = acc;
    }
}

// ---------------------------------------------------------------------------
// k_insum: segment-sum  in_e[t,s] = sum_{e: assign==s} S_e[t,e]  (2% density)
// One block per timestep; LDS float atomics (few dozen hits per block).
// ---------------------------------------------------------------------------
__global__ void k_insum(const float* __restrict__ Se, const float* __restrict__ Si,
                        const int* __restrict__ ae, const int* __restrict__ ai,
                        float* __restrict__ in_e, float* __restrict__ in_i,
                        int T, int E, int I)
{
    int t = blockIdx.x;
    __shared__ float le[SUB], li[SUB];
    if (threadIdx.x < SUB) { le[threadIdx.x] = 0.f; li[threadIdx.x] = 0.f; }
    __syncthreads();
    for (int e = threadIdx.x; e < E; e += blockDim.x) {
        float v = Se[(size_t)t * E + e];
        if (v != 0.f) atomicAdd(&le[ae[e]], v);
    }
    for (int i = threadIdx.x; i < I; i += blockDim.x) {
        float v = Si[(size_t)t * I + i];
        if (v != 0.f) atomicAdd(&li[ai[i]], v);
    }
    __syncthreads();
    if (threadIdx.x < SUB) {
        in_e[t * SUB + threadIdx.x] = le[threadIdx.x];
        in_i[t * SUB + threadIdx.x] = li[threadIdx.x];
    }
}

// ---------------------------------------------------------------------------
// k_conv: 200-tap causal conv  syn_ns[t,s] = sum_j in_e[t-j,s]ke[s,j] + in_i..ki
// ---------------------------------------------------------------------------
__global__ void k_conv(const float* __restrict__ in_e, const float* __restrict__ in_i,
                       const float* __restrict__ ke, const float* __restrict__ ki,
                       float* __restrict__ syn_ns, int T)
{
    int idx = blockIdx.x * blockDim.x + threadIdx.x;
    if (idx >= T * SUB) return;
    int s = idx % SUB, t = idx / SUB;
    float acc = 0.f;
    int jmax = min(TSYN - 1, t);
    for (int j = 0; j <= jmax; ++j) {
        int u = (t - j) * SUB + s;
        acc += in_e[u] * ke[s * TSYN + j] + in_i[u] * ki[s * TSYN + j];
    }
    syn_ns[idx] = acc;
}

// ---------------------------------------------------------------------------
// k_spk: serial spike recurrence, one wave. Z held as a wave ballot mask;
// coupling term P[c] = sum_{c'} C_s[c,c']*W_s_prop[c'] over set bits, with
// the 19x19 weight matrix unrolled into per-lane registers.
// ---------------------------------------------------------------------------
__global__ __launch_bounds__(64) void k_spk(const float* __restrict__ in_e, const float* __restrict__ in_i,
                      const float* __restrict__ W_s_syn, const float* __restrict__ Theta_s,
                      const float* __restrict__ spike_decay, const float* __restrict__ C_den,
                      const float* __restrict__ W_s_prop,
                      float* __restrict__ Zout, float* __restrict__ Xout, int T)
{
    int c = threadIdx.x;
    bool act = c < NC;
    float M[NC];
    #pragma unroll
    for (int j = 0; j < NC; ++j)
        M[j] = act ? C_den[(c + 1) * SUB + (j + 1)] * W_s_prop[j] : 0.f;
    float theta = act ? Theta_s[c] : 0.f;
    float decay = act ? spike_decay[c] : 0.f;
    float ws0 = act ? W_s_syn[(c + 1) * 2 + 0] : 0.f;
    float ws1 = act ? W_s_syn[(c + 1) * 2 + 1] : 0.f;

    float x = 0.f;
    unsigned long long zmask = 0ull;
    float se_cur = act ? in_e[c + 1] : 0.f;
    float si_cur = act ? in_i[c + 1] : 0.f;

    for (int t = 0; t < T; ++t) {
        // prefetch next step's inputs (independent of this step's chain)
        float se_nxt = 0.f, si_nxt = 0.f;
        if (act && t + 1 < T) {
            se_nxt = in_e[(t + 1) * SUB + c + 1];
            si_nxt = in_i[(t + 1) * SUB + c + 1];
        }
        float syn = se_cur * ws0 + si_cur * ws1;
        float P = 0.f;
        #pragma unroll
        for (int j = 0; j < NC; ++j)
            P += ((zmask >> j) & 1ull) ? M[j] : 0.f;
        float xin = x * decay + syn + P + theta;   // same order as reference
        bool z = xin >= 0.f;
        zmask = __ballot(act && z);
        x = z ? 0.f : xin;
        if (act) {
            Zout[t * NC + c] = z ? 1.f : 0.f;
            Xout[t * NC + c] = x;
        }
        se_cur = se_nxt; si_cur = si_nxt;
    }
}

// ---------------------------------------------------------------------------
// k_pz: PZ[u,s] = sum_c Z[u,c] * C_den[s, c+1]   (parallel over u,s)
// ---------------------------------------------------------------------------
__global__ void k_pz(const float* __restrict__ Z, const float* __restrict__ C_den,
                     float* __restrict__ PZ, int T)
{
    int idx = blockIdx.x * blockDim.x + threadIdx.x;
    if (idx >= T * SUB) return;
    int s = idx % SUB, u = idx / SUB;
    float acc = 0.f;
    #pragma unroll
    for (int c = 0; c < NC; ++c)
        acc += Z[u * NC + c] * C_den[s * SUB + c + 1];
    PZ[idx] = acc;
}

// ---------------------------------------------------------------------------
// k_A: A[t,s] = syn_ns + Theta_ns + f_prop (+ f_hist for s>=1); both f_* are
// 50-tap causal convs over the known Z/PZ sequences, delayed by one step.
// ---------------------------------------------------------------------------
__global__ void k_A(const float* __restrict__ syn_ns, const float* __restrict__ PZ,
                    const float* __restrict__ Z, const float* __restrict__ histk,
                    const float* __restrict__ propk, const float* __restrict__ Theta_ns,
                    float* __restrict__ A, int T)
{
    int idx = blockIdx.x * blockDim.x + threadIdx.x;
    if (idx >= T * SUB) return;
    int s = idx % SUB, t = idx / SUB;
    float acc = syn_ns[idx] + Theta_ns[s];
    int jmax = min(THIST - 1, t - 1);
    for (int j = 0; j <= jmax; ++j)
        acc += propk[s * THIST + j] * PZ[(t - 1 - j) * SUB + s];
    if (s > 0) {
        int c = s - 1;
        for (int j = 0; j <= jmax; ++j)
            acc += histk[c * THIST + j] * Z[(t - 1 - j) * NC + c];
    }
    A[idx] = acc;
}

// ---------------------------------------------------------------------------
// k_y: serial Y recurrence, one wave. Y broadcast through LDS each step.
// Y(t) = sigmoid(A(t) + C_den @ Y(t-1)) * W_ns_sub
// ---------------------------------------------------------------------------
__global__ __launch_bounds__(64) void k_y(const float* __restrict__ A, const float* __restrict__ C_den,
                    const float* __restrict__ W_ns_sub, const float* __restrict__ V_o,
                    float* __restrict__ Vout, float* __restrict__ Yout, int T)
{
    __shared__ float Ysh[SUB];
    int s = threadIdx.x;
    bool act = s < SUB;
    float Crow[SUB];
    #pragma unroll
    for (int j = 0; j < SUB; ++j)
        Crow[j] = act ? C_den[s * SUB + j] : 0.f;
    float wsub = act ? W_ns_sub[s] : 0.f;
    float vo = V_o[0];
    if (act) Ysh[s] = 0.f;
    __syncthreads();
    float acur = act ? A[s] : 0.f;
    for (int t = 0; t < T; ++t) {
        float anxt = (act && t + 1 < T) ? A[(t + 1) * SUB + s] : 0.f;
        float u = acur;
        #pragma unroll
        for (int j = 0; j < SUB; ++j)
            u += Crow[j] * Ysh[j];
        float y = wsub / (1.f + __expf(-u));
        __syncthreads();
        if (act) Ysh[s] = y;
        __syncthreads();
        if (s == 0) Vout[t] = y + vo;
        else if (act) Yout[t * NC + (s - 1)] = y;
        acur = anxt;
    }
}

// ---------------------------------------------------------------------------
extern "C" void kernel_launch(void* const* d_in, const int* in_sizes, int n_in,
                              void* d_out, int out_size, void* d_ws, size_t ws_size,
                              hipStream_t stream)
{
    const float* S_e          = (const float*)d_in[0];
    const float* S_i          = (const float*)d_in[1];
    const float* C_den        = (const float*)d_in[2];
    const float* C_syn_e      = (const float*)d_in[3];
    const float* C_syn_i      = (const float*)d_in[4];
    const float* W_s_syn      = (const float*)d_in[5];
    const float* W_ns_syn     = (const float*)d_in[6];
    const float* Delta_ns_syn = (const float*)d_in[7];
    const float* W_ns_sub     = (const float*)d_in[8];
    const float* V_o          = (const float*)d_in[9];
    const float* Theta_s      = (const float*)d_in[10];
    const float* Theta_ns     = (const float*)d_in[11];
    const float* W_ns_hist    = (const float*)d_in[12];
    const float* W_s_prop     = (const float*)d_in[13];
    const float* W_ns_prop    = (const float*)d_in[14];
    const float* spike_decay  = (const float*)d_in[15];

    int E = in_sizes[3] / SUB;
    int I = in_sizes[4] / SUB;
    int T = in_sizes[0] / E;

    float* out  = (float*)d_out;
    float* Vout = out;                         // [T]
    float* Yout = out + (size_t)T;             // [T, 19]
    float* Zout = out + (size_t)T * (1 + NC);  // [T, 19]
    float* Xout = out + (size_t)T * (1 + 2*NC);// [T, 19]

    float* w      = (float*)d_ws;
    float* in_e   = w;  w += (size_t)T * SUB;
    float* in_i   = w;  w += (size_t)T * SUB;
    float* syn_ns = w;  w += (size_t)T * SUB;
    float* PZ     = w;  w += (size_t)T * SUB;
    float* Abuf   = w;  w += (size_t)T * SUB;
    float* ke     = w;  w += SUB * TSYN;
    float* ki     = w;  w += SUB * TSYN;
    float* histk  = w;  w += NC * THIST;
    float* propk  = w;  w += SUB * THIST;
    int*   ae     = (int*)w;
    int*   ai     = ae + E;

    int nprep = E + I + SUB * 2 * TSYN + NC * THIST + SUB * THIST;
    hipLaunchKernelGGL(k_prep, dim3((nprep + 255) / 256), dim3(256), 0, stream,
                       C_syn_e, C_syn_i, W_ns_syn, Delta_ns_syn, W_ns_hist, W_ns_prop,
                       ae, ai, ke, ki, histk, propk, E, I);
    hipLaunchKernelGGL(k_insum, dim3(T), dim3(256), 0, stream,
                       S_e, S_i, ae, ai, in_e, in_i, T, E, I);
    hipLaunchKernelGGL(k_conv, dim3((T * SUB + 255) / 256), dim3(256), 0, stream,
                       in_e, in_i, ke, ki, syn_ns, T);
    hipLaunchKernelGGL(k_spk, dim3(1), dim3(64), 0, stream,
                       in_e, in_i, W_s_syn, Theta_s, spike_decay, C_den, W_s_prop,
                       Zout, Xout, T);
    hipLaunchKernelGGL(k_pz, dim3((T * SUB + 255) / 256), dim3(256), 0, stream,
                       Zout, C_den, PZ, T);
    hipLaunchKernelGGL(k_A, dim3((T * SUB + 255) / 256), dim3(256), 0, stream,
                       syn_ns, PZ, Zout, histk, propk, Theta_ns, Abuf, T);
    hipLaunchKernelGGL(k_y, dim3(1), dim3(64), 0, stream,
                       Abuf, C_den, W_ns_sub, V_o, Vout, Yout, T);
}

// Round 2
// 4836.058 us; speedup vs baseline: 1.4920x; 1.4920x over previous
//
#include <hip/hip_runtime.h>
#include <math.h>

#define SUB 20      // sub_no
#define NC 19       // sub_no - 1
#define TSYN 200
#define THIST 50
#define BNUM 3
#define CH 512      // serial-kernel LDS chunk length (power of 2)
#define CHP (CH+4)  // padded row stride (breaks 32-bank alignment for b128 reads)

// ---------------------------------------------------------------------------
// k_prep: assignment indices from one-hot C_syn, plus the three alpha-basis
// kernels (syn with delta shift, hist, prop). All tiny, one launch.
// ---------------------------------------------------------------------------
__global__ void k_prep(const float* __restrict__ C_syn_e, const float* __restrict__ C_syn_i,
                       const float* __restrict__ W_ns_syn, const float* __restrict__ Delta_ns_syn,
                       const float* __restrict__ W_ns_hist, const float* __restrict__ W_ns_prop,
                       int* __restrict__ ae, int* __restrict__ ai,
                       float* __restrict__ ke, float* __restrict__ ki,
                       float* __restrict__ histk, float* __restrict__ propk,
                       int E, int I)
{
    int idx = blockIdx.x * blockDim.x + threadIdx.x;
    if (idx < E) {
        int a = 0;
        for (int s = 0; s < SUB; ++s) if (C_syn_e[(size_t)s * E + idx] != 0.f) a = s;
        ae[idx] = a;
        return;
    }
    idx -= E;
    if (idx < I) {
        int a = 0;
        for (int s = 0; s < SUB; ++s) if (C_syn_i[(size_t)s * I + idx] != 0.f) a = s;
        ai[idx] = a;
        return;
    }
    idx -= I;
    if (idx < SUB * 2 * TSYN) {
        int j   = idx % TSYN;
        int rem = idx / TSYN;
        int c2  = rem & 1;
        int s   = rem >> 1;
        float delta = expf(Delta_ns_syn[s * 2 + c2]);
        float ts = fmaxf((float)j - delta, 0.f);
        float acc = 0.f;
        for (int b = 0; b < BNUM; ++b) {
            float tau = expf((float)b);
            float tt = ts / tau;
            acc += W_ns_syn[s * 6 + b * 2 + c2] * tt * expf(-tt);
        }
        if (c2 == 0) ke[s * TSYN + j] = acc; else ki[s * TSYN + j] = acc;
        return;
    }
    idx -= SUB * 2 * TSYN;
    if (idx < NC * THIST) {
        int j = idx % THIST, c = idx / THIST;
        float acc = 0.f;
        for (int b = 0; b < BNUM; ++b) {
            float tau = expf((float)b);
            float tt = (float)j / tau;
            acc += W_ns_hist[c * 3 + b] * tt * expf(-tt);
        }
        histk[c * THIST + j] = acc;
        return;
    }
    idx -= NC * THIST;
    if (idx < SUB * THIST) {
        int j = idx % THIST, s = idx / THIST;
        float acc = 0.f;
        for (int b = 0; b < BNUM; ++b) {
            float tau = expf((float)b);
            float tt = (float)j / tau;
            acc += W_ns_prop[s * 3 + b] * tt * expf(-tt);
        }
        propk[s * THIST + j] = acc;
    }
}

// ---------------------------------------------------------------------------
// k_insum: segment-sum per timestep, writing TRANSPOSED [s][t] layouts plus
// the fused somatic synaptic drive syn_sT[c][t] (c = sub-1).
// ---------------------------------------------------------------------------
__global__ void k_insum(const float* __restrict__ Se, const float* __restrict__ Si,
                        const int* __restrict__ ae, const int* __restrict__ ai,
                        const float* __restrict__ W_s_syn,
                        float* __restrict__ in_eT, float* __restrict__ in_iT,
                        float* __restrict__ syn_sT,
                        int T, int E, int I)
{
    int t = blockIdx.x;
    __shared__ float le[SUB], li[SUB];
    if (threadIdx.x < SUB) { le[threadIdx.x] = 0.f; li[threadIdx.x] = 0.f; }
    __syncthreads();
    for (int e = threadIdx.x; e < E; e += blockDim.x) {
        float v = Se[(size_t)t * E + e];
        if (v != 0.f) atomicAdd(&le[ae[e]], v);
    }
    for (int i = threadIdx.x; i < I; i += blockDim.x) {
        float v = Si[(size_t)t * I + i];
        if (v != 0.f) atomicAdd(&li[ai[i]], v);
    }
    __syncthreads();
    int s = threadIdx.x;
    if (s < SUB) {
        in_eT[(size_t)s * T + t] = le[s];
        in_iT[(size_t)s * T + t] = li[s];
        if (s >= 1)
            syn_sT[(size_t)(s - 1) * T + t] =
                le[s] * W_s_syn[s * 2 + 0] + li[s] * W_s_syn[s * 2 + 1];
    }
}

// ---------------------------------------------------------------------------
// k_conv: 200-tap causal conv on transposed layouts (coalesced over t).
// ---------------------------------------------------------------------------
__global__ void k_conv(const float* __restrict__ in_eT, const float* __restrict__ in_iT,
                       const float* __restrict__ ke, const float* __restrict__ ki,
                       float* __restrict__ syn_nsT, int T)
{
    int idx = blockIdx.x * blockDim.x + threadIdx.x;
    if (idx >= SUB * T) return;
    int s = idx / T, t = idx % T;
    float acc = 0.f;
    int jmax = min(TSYN - 1, t);
    for (int j = 0; j <= jmax; ++j)
        acc += in_eT[(size_t)s * T + t - j] * ke[s * TSYN + j]
             + in_iT[(size_t)s * T + t - j] * ki[s * TSYN + j];
    syn_nsT[idx] = acc;
}

// ---------------------------------------------------------------------------
// k_spk: serial spike recurrence, one wave. syn staged to LDS in CH-step
// chunks (coalesced float4); per-step cross-lane Z coupling via v_readlane
// + fmac (z in {0,1} float per lane -> sums bit-identical to select+add).
// ---------------------------------------------------------------------------
__global__ __launch_bounds__(64) void k_spk(const float* __restrict__ syn_sT,
                      const float* __restrict__ Theta_s, const float* __restrict__ spike_decay,
                      const float* __restrict__ C_den, const float* __restrict__ W_s_prop,
                      float* __restrict__ Zout, float* __restrict__ Xout, int T)
{
    __shared__ float S[NC * CHP];
    int lane = threadIdx.x;
    int c = lane;
    bool act = c < NC;
    float M[NC];
    #pragma unroll
    for (int j = 0; j < NC; ++j)
        M[j] = act ? C_den[(c + 1) * SUB + (j + 1)] * W_s_prop[j] : 0.f;
    float theta = act ? Theta_s[c] : 0.f;
    float decay = act ? spike_decay[c] : 0.f;

    float x = 0.f, z = 0.f;
    for (int t0 = 0; t0 < T; t0 += CH) {
        int len = min(CH, T - t0);
        __syncthreads();
        for (int r = lane; r < (NC * CH) / 4; r += 64) {
            int e = r * 4;
            int cc = e >> 9;          // e / CH
            int tl = e & (CH - 1);    // e % CH
            if (tl < len) {
                float4 v = *(const float4*)(syn_sT + (size_t)cc * T + t0 + tl);
                *(float4*)(&S[cc * CHP + tl]) = v;
            }
        }
        __syncthreads();
        float4 cur = act ? *(float4*)(&S[c * CHP]) : make_float4(0.f, 0.f, 0.f, 0.f);
        for (int g = 0; g < len; g += 4) {
            float4 nxt = (act && g + 4 < len) ? *(float4*)(&S[c * CHP + g + 4]) : cur;
            #pragma unroll
            for (int q = 0; q < 4; ++q) {
                float syn = (q == 0) ? cur.x : (q == 1) ? cur.y : (q == 2) ? cur.z : cur.w;
                float P = 0.f;
                #pragma unroll
                for (int j = 0; j < NC; ++j) {
                    float zj = __int_as_float(__builtin_amdgcn_readlane(__float_as_int(z), j));
                    P += zj * M[j];   // z in {0,1}: exact, same order as R1 select+add
                }
                float xin = x * decay + syn;
                xin += P;
                xin += theta;
                int t = t0 + g + q;
                if (t < T) {
                    bool zb = xin >= 0.f;
                    z = zb ? 1.f : 0.f;
                    x = zb ? 0.f : xin;
                    if (act) {
                        Zout[(size_t)t * NC + c] = z;
                        Xout[(size_t)t * NC + c] = x;
                    }
                }
            }
            cur = nxt;
        }
    }
}

// ---------------------------------------------------------------------------
// k_pz: PZ_T[s][u] = sum_c Z[u,c] * C_den[s, c+1]
// ---------------------------------------------------------------------------
__global__ void k_pz(const float* __restrict__ Z, const float* __restrict__ C_den,
                     float* __restrict__ PZ_T, int T)
{
    int idx = blockIdx.x * blockDim.x + threadIdx.x;
    if (idx >= SUB * T) return;
    int s = idx / T, u = idx % T;
    float acc = 0.f;
    #pragma unroll
    for (int c = 0; c < NC; ++c)
        acc += Z[(size_t)u * NC + c] * C_den[s * SUB + c + 1];
    PZ_T[idx] = acc;
}

// ---------------------------------------------------------------------------
// k_A: A_T[s][t] = syn_ns + Theta_ns + f_prop (+ f_hist for s>=1)
// ---------------------------------------------------------------------------
__global__ void k_A(const float* __restrict__ syn_nsT, const float* __restrict__ PZ_T,
                    const float* __restrict__ Z, const float* __restrict__ histk,
                    const float* __restrict__ propk, const float* __restrict__ Theta_ns,
                    float* __restrict__ A_T, int T)
{
    int idx = blockIdx.x * blockDim.x + threadIdx.x;
    if (idx >= SUB * T) return;
    int s = idx / T, t = idx % T;
    float acc = syn_nsT[idx] + Theta_ns[s];
    int jmax = min(THIST - 1, t - 1);
    for (int j = 0; j <= jmax; ++j)
        acc += propk[s * THIST + j] * PZ_T[(size_t)s * T + t - 1 - j];
    if (s > 0) {
        int c = s - 1;
        for (int j = 0; j <= jmax; ++j)
            acc += histk[c * THIST + j] * Z[(size_t)(t - 1 - j) * NC + c];
    }
    A_T[idx] = acc;
}

// ---------------------------------------------------------------------------
// k_y: serial Y recurrence, one wave. A staged to LDS in chunks; Y broadcast
// via v_readlane (no LDS round-trip on the chain).
// ---------------------------------------------------------------------------
__global__ __launch_bounds__(64) void k_y(const float* __restrict__ A_T,
                    const float* __restrict__ C_den, const float* __restrict__ W_ns_sub,
                    const float* __restrict__ V_o,
                    float* __restrict__ Vout, float* __restrict__ Yout, int T)
{
    __shared__ float S[SUB * CHP];
    int lane = threadIdx.x;
    int s = lane;
    bool act = s < SUB;
    float Crow[SUB];
    #pragma unroll
    for (int j = 0; j < SUB; ++j)
        Crow[j] = act ? C_den[s * SUB + j] : 0.f;
    float wsub = act ? W_ns_sub[s] : 0.f;
    float vo = V_o[0];

    float y = 0.f;
    for (int t0 = 0; t0 < T; t0 += CH) {
        int len = min(CH, T - t0);
        __syncthreads();
        for (int r = lane; r < (SUB * CH) / 4; r += 64) {
            int e = r * 4;
            int cc = e >> 9;
            int tl = e & (CH - 1);
            if (tl < len) {
                float4 v = *(const float4*)(A_T + (size_t)cc * T + t0 + tl);
                *(float4*)(&S[cc * CHP + tl]) = v;
            }
        }
        __syncthreads();
        float4 cur = act ? *(float4*)(&S[s * CHP]) : make_float4(0.f, 0.f, 0.f, 0.f);
        for (int g = 0; g < len; g += 4) {
            float4 nxt = (act && g + 4 < len) ? *(float4*)(&S[s * CHP + g + 4]) : cur;
            #pragma unroll
            for (int q = 0; q < 4; ++q) {
                float a = (q == 0) ? cur.x : (q == 1) ? cur.y : (q == 2) ? cur.z : cur.w;
                // 4-accumulator tree: safe, Y path is smooth (no threshold)
                float u0 = a, u1 = 0.f, u2 = 0.f, u3 = 0.f;
                #pragma unroll
                for (int j = 0; j < SUB; j += 4) {
                    u0 += Crow[j]     * __int_as_float(__builtin_amdgcn_readlane(__float_as_int(y), j));
                    u1 += Crow[j + 1] * __int_as_float(__builtin_amdgcn_readlane(__float_as_int(y), j + 1));
                    u2 += Crow[j + 2] * __int_as_float(__builtin_amdgcn_readlane(__float_as_int(y), j + 2));
                    u3 += Crow[j + 3] * __int_as_float(__builtin_amdgcn_readlane(__float_as_int(y), j + 3));
                }
                float u = (u0 + u1) + (u2 + u3);
                int t = t0 + g + q;
                if (t < T) {
                    y = wsub / (1.f + __expf(-u));
                    if (act) {
                        float* p = (s == 0) ? (Vout + t) : (Yout + (size_t)t * NC + (s - 1));
                        *p = (s == 0) ? y + vo : y;
                    }
                }
            }
            cur = nxt;
        }
    }
}

// ---------------------------------------------------------------------------
extern "C" void kernel_launch(void* const* d_in, const int* in_sizes, int n_in,
                              void* d_out, int out_size, void* d_ws, size_t ws_size,
                              hipStream_t stream)
{
    const float* S_e          = (const float*)d_in[0];
    const float* S_i          = (const float*)d_in[1];
    const float* C_den        = (const float*)d_in[2];
    const float* C_syn_e      = (const float*)d_in[3];
    const float* C_syn_i      = (const float*)d_in[4];
    const float* W_s_syn      = (const float*)d_in[5];
    const float* W_ns_syn     = (const float*)d_in[6];
    const float* Delta_ns_syn = (const float*)d_in[7];
    const float* W_ns_sub     = (const float*)d_in[8];
    const float* V_o          = (const float*)d_in[9];
    const float* Theta_s      = (const float*)d_in[10];
    const float* Theta_ns     = (const float*)d_in[11];
    const float* W_ns_hist    = (const float*)d_in[12];
    const float* W_s_prop     = (const float*)d_in[13];
    const float* W_ns_prop    = (const float*)d_in[14];
    const float* spike_decay  = (const float*)d_in[15];

    int E = in_sizes[3] / SUB;
    int I = in_sizes[4] / SUB;
    int T = in_sizes[0] / E;

    float* out  = (float*)d_out;
    float* Vout = out;                           // [T]
    float* Yout = out + (size_t)T;               // [T, 19]
    float* Zout = out + (size_t)T * (1 + NC);    // [T, 19]
    float* Xout = out + (size_t)T * (1 + 2*NC);  // [T, 19]

    float* w       = (float*)d_ws;
    float* in_eT   = w;  w += (size_t)SUB * T;   // aliased as A_T after k_conv
    float* in_iT   = w;  w += (size_t)SUB * T;
    float* syn_sT  = w;  w += (size_t)NC * T;
    float* syn_nsT = w;  w += (size_t)SUB * T;
    float* PZ_T    = w;  w += (size_t)SUB * T;
    float* ke      = w;  w += SUB * TSYN;
    float* ki      = w;  w += SUB * TSYN;
    float* histk   = w;  w += NC * THIST;
    float* propk   = w;  w += SUB * THIST;
    int*   ae      = (int*)w;
    int*   ai      = ae + E;
    float* A_T     = in_eT;   // in_eT dead after k_conv

    int nprep = E + I + SUB * 2 * TSYN + NC * THIST + SUB * THIST;
    hipLaunchKernelGGL(k_prep, dim3((nprep + 255) / 256), dim3(256), 0, stream,
                       C_syn_e, C_syn_i, W_ns_syn, Delta_ns_syn, W_ns_hist, W_ns_prop,
                       ae, ai, ke, ki, histk, propk, E, I);
    hipLaunchKernelGGL(k_insum, dim3(T), dim3(256), 0, stream,
                       S_e, S_i, ae, ai, W_s_syn, in_eT, in_iT, syn_sT, T, E, I);
    hipLaunchKernelGGL(k_conv, dim3((SUB * T + 255) / 256), dim3(256), 0, stream,
                       in_eT, in_iT, ke, ki, syn_nsT, T);
    hipLaunchKernelGGL(k_spk, dim3(1), dim3(64), 0, stream,
                       syn_sT, Theta_s, spike_decay, C_den, W_s_prop, Zout, Xout, T);
    hipLaunchKernelGGL(k_pz, dim3((SUB * T + 255) / 256), dim3(256), 0, stream,
                       Zout, C_den, PZ_T, T);
    hipLaunchKernelGGL(k_A, dim3((SUB * T + 255) / 256), dim3(256), 0, stream,
                       syn_nsT, PZ_T, Zout, histk, propk, Theta_ns, A_T, T);
    hipLaunchKernelGGL(k_y, dim3(1), dim3(64), 0, stream,
                       A_T, C_den, W_ns_sub, V_o, Vout, Yout, T);
}